// Round 10
// baseline (608.005 us; speedup 1.0000x reference)
//
#include <hip/hip_runtime.h>
#include <hip/hip_bf16.h>
#include <stdint.h>
#include <math.h>

#define IN_DIM 256
#define HID_DIM 256
#define OUT_DIM 128

typedef __attribute__((ext_vector_type(8))) short short8;
typedef __attribute__((ext_vector_type(4))) float floatx4;

__device__ __forceinline__ float bf2f(ushort u) {
  union { uint32_t i; float f; } v; v.i = ((uint32_t)u) << 16; return v.f;
}
__device__ __forceinline__ ushort f2bf(float f) {
  union { float f; uint32_t u; } v; v.f = f;
  uint32_t u = v.u;
  uint32_t r = u + 0x7fffu + ((u >> 16) & 1u);  // RNE; finite values only here
  return (ushort)(r >> 16);
}
__device__ __forceinline__ short8 pack_bf16x8(float4 a, float4 b) {
  short8 r;
  r[0] = (short)f2bf(a.x); r[1] = (short)f2bf(a.y);
  r[2] = (short)f2bf(a.z); r[3] = (short)f2bf(a.w);
  r[4] = (short)f2bf(b.x); r[5] = (short)f2bf(b.y);
  r[6] = (short)f2bf(b.z); r[7] = (short)f2bf(b.w);
  return r;
}

// Fragment-packed B layout: element (outcol n, kdim k) ->
//   pidx = (k>>3)*2048 + (n&15)*128 + (n>>4)*8 + (k&7)
// wave at k-step ks reads from ONE base ((ks*4+quad)*16+l15)*128
// 16 contiguous 16B fragments at immediate offsets j*16B.
__device__ __forceinline__ int bpack_idx(int n, int k) {
  return ((k >> 3) * 2048) + ((n & 15) * 128) + ((n >> 4) * 8) + (k & 7);
}

// ---- dispatch A: degree counting (2 edges/thread) || packed weight prep ----
__global__ void deg_prep_kernel(const int* __restrict__ src, const int* __restrict__ dst,
                                int* __restrict__ out_deg, int* __restrict__ in_deg,
                                int E, int eblocks,
                                const float* __restrict__ W1, const float* __restrict__ W2,
                                const float* __restrict__ W3, const float* __restrict__ b2,
                                const float* __restrict__ b3, const float* __restrict__ fcW,
                                ushort* __restrict__ W1Tp, ushort* __restrict__ WcTp,
                                float* __restrict__ bcat, ushort* __restrict__ fcWp) {
  int b = blockIdx.x, t = threadIdx.x;
  if (b < eblocks) {
    int e = (b * 256 + t) * 2;
    if (e + 1 < E) {
      int2 s = *(const int2*)(src + e);
      int2 d = *(const int2*)(dst + e);
      atomicAdd(&out_deg[s.x], 1);
      atomicAdd(&out_deg[s.y], 1);
      atomicAdd(&in_deg[d.x], 1);
      atomicAdd(&in_deg[d.y], 1);
    } else if (e < E) {
      atomicAdd(&out_deg[src[e]], 1);
      atomicAdd(&in_deg[dst[e]], 1);
    }
  } else if (b < eblocks + 256) {
    int k = b - eblocks;  // kdim 0..255
    int nn = t;           // outcol 0..255
    W1Tp[bpack_idx(nn, k)] = f2bf(W1[k * 256 + nn]);
    WcTp[bpack_idx(nn, k)] = f2bf((nn < 128) ? W2[k * 128 + nn] : W3[k * 128 + (nn - 128)]);
    if (k == 0) bcat[nn] = (nn < 128) ? b2[nn] : b3[nn - 128];
  } else {
    int k = b - eblocks - 256;  // fcW row = OUTPUT COL 0..255
    int nn = t;                 // fcW col = kdim 0..255
    fcWp[bpack_idx(k, nn)] = f2bf(fcW[k * 256 + nn]);
  }
}

// ---- MEGA: block 0 = scan(in_deg->row_ptr, batched int4);
//      blocks [1,1+gb)      = seq_fts GEMM (A=features fp32 direct, B=fcWp, C fp32)
//      blocks [1+gb,1+2gb)  = XW1 GEMM    (A=features fp32 direct, B=W1Tp, C bf16)
// BARRIER-FREE streaming GEMM, M-TILE 64: wave owns 16 rows, acc = 16 floatx4
// (64 VGPR) -> launch_bounds(256,4) caps at 128 VGPR without spilling, grid 2x
// denser (6.1 blocks/CU) for latency hiding.
__global__ __launch_bounds__(256, 4) void mega_kernel(
    const float* __restrict__ feat, const ushort* __restrict__ fcWp,
    const ushort* __restrict__ W1Tp,
    float* __restrict__ s_out, ushort* __restrict__ xw1_bf,
    const int* __restrict__ in_deg, int* __restrict__ row_ptr, int n, int M, int gb) {
  __shared__ int slds[256];
  int b = blockIdx.x;
  int t = threadIdx.x;

  if (b == 0) {
    // ============ scan role: latency-batched (8 int4 loads in flight) ============
    int CH = (n + 255) >> 8; CH = (CH + 3) & ~3;   // elems/thread, mult of 4
    int base = t * CH;
    int s = 0;
    if (base + CH <= n) {
      const int4* p = (const int4*)(in_deg + base);
      int c4 = CH >> 2;
#pragma unroll 8
      for (int j = 0; j < c4; ++j) { int4 q = p[j]; s += q.x + q.y + q.z + q.w; }
    } else {
      for (int i = base; i < n; ++i) s += in_deg[i];
    }
    slds[t] = s;
    __syncthreads();
    for (int off = 1; off < 256; off <<= 1) {
      int add = (t >= off) ? slds[t - off] : 0;
      __syncthreads();
      slds[t] += add;
      __syncthreads();
    }
    int run = slds[t] - s;                    // exclusive prefix
    if (t == 0) row_ptr[0] = 0;
    if (base + CH <= n) {
      const int4* p = (const int4*)(in_deg + base);
      int c4 = CH >> 2;
#pragma unroll 4
      for (int j = 0; j < c4; ++j) {
        int4 q = p[j];
        int i = base + j * 4;
        run += q.x; row_ptr[i + 1] = run;
        run += q.y; row_ptr[i + 2] = run;
        run += q.z; row_ptr[i + 3] = run;
        run += q.w; row_ptr[i + 4] = run;
      }
    } else {
      for (int i = base; i < n; ++i) { run += in_deg[i]; row_ptr[i + 1] = run; }
    }
    return;
  }

  // ============ GEMM roles (barrier-free streaming, 64-row tile) ============
  int bb = b - 1;
  bool isSeq = bb < gb;
  int m0 = (isSeq ? bb : bb - gb) * 64;
  const ushort* Bp = isSeq ? fcWp : W1Tp;
  int wave = t >> 6, lane = t & 63;
  int wm = wave * 16;
  int l15 = lane & 15, quad = lane >> 4;

  int r0 = m0 + wm + l15; if (r0 > M - 1) r0 = M - 1;
  const float* pa0 = feat + (size_t)r0 * 256 + quad * 8;

  floatx4 acc[16];
#pragma unroll
  for (int j = 0; j < 16; ++j) acc[j] = (floatx4)(0.f);

#pragma unroll
  for (int ks = 0; ks < 8; ++ks) {
    float4 v0 = *(const float4*)(pa0 + ks * 32);
    float4 v1 = *(const float4*)(pa0 + ks * 32 + 4);
    short8 a0 = pack_bf16x8(v0, v1);
    const ushort* pb = Bp + ((ks * 4 + quad) * 16 + l15) * 128;
#pragma unroll
    for (int j = 0; j < 16; ++j) {
      short8 bv = *(const short8*)(pb + j * 8);
      acc[j] = __builtin_amdgcn_mfma_f32_16x16x32_bf16(a0, bv, acc[j], 0, 0, 0);
    }
  }

  if (isSeq) {
#pragma unroll
    for (int j = 0; j < 16; ++j) {
      int col = j * 16 + l15;
#pragma unroll
      for (int r = 0; r < 4; ++r) {
        int row = m0 + wm + quad * 4 + r;
        if (row < M) s_out[(size_t)row * 256 + col] = acc[j][r];
      }
    }
  } else {
#pragma unroll
    for (int j = 0; j < 16; ++j) {
      int col = j * 16 + l15;
#pragma unroll
      for (int r = 0; r < 4; ++r) {
        int row = m0 + wm + quad * 4 + r;
        if (row < M) xw1_bf[(size_t)row * 256 + col] = f2bf(acc[j][r]);
      }
    }
  }
}

// ---- bucket edges by dst (CSR fill); 2 edges/thread; record {src, bits(rsqrt(out_deg))} ----
__global__ void fill_kernel(const int* __restrict__ src, const int* __restrict__ dst,
                            const int* __restrict__ row_ptr, int* __restrict__ fill_cnt,
                            const int* __restrict__ out_deg,
                            int2* __restrict__ edge_sw, int E) {
  int e = (blockIdx.x * 256 + threadIdx.x) * 2;
  if (e + 1 < E) {
    int2 s = *(const int2*)(src + e);
    int2 d = *(const int2*)(dst + e);
    int pos0 = row_ptr[d.x] + atomicAdd(&fill_cnt[d.x], 1);
    int od0 = out_deg[s.x]; if (od0 < 1) od0 = 1;
    int2 r0; r0.x = s.x; r0.y = __float_as_int(rsqrtf((float)od0));
    edge_sw[pos0] = r0;
    int pos1 = row_ptr[d.y] + atomicAdd(&fill_cnt[d.y], 1);
    int od1 = out_deg[s.y]; if (od1 < 1) od1 = 1;
    int2 r1; r1.x = s.y; r1.y = __float_as_int(rsqrtf((float)od1));
    edge_sw[pos1] = r1;
  } else if (e < E) {
    int d = dst[e]; int s = src[e];
    int pos = row_ptr[d] + atomicAdd(&fill_cnt[d], 1);
    int od = out_deg[s]; if (od < 1) od = 1;
    int2 r; r.x = s; r.y = __float_as_int(rsqrtf((float)od));
    edge_sw[pos] = r;
  }
}

// ---- aggregation over TRANSFORMED features with fused epilogue ----
// mode 0 (h):  out32[n][256] = relu(acc*inn + bias[dim]), outbf = bf16 copy
// mode 1 (z):  dims 0..127 = mean-part, 128..255 = logstd-part ->
//              z[n][c] = relu(am*inn+b2[c]) + noise[n][c]*exp(al*inn+b3[c])
__global__ __launch_bounds__(256) void agg_kernel(
    const ushort* __restrict__ x, const int* __restrict__ row_ptr,
    const int2* __restrict__ edge_sw,
    const float* __restrict__ bias, const float* __restrict__ noise,
    float* __restrict__ out32, ushort* __restrict__ outbf, int N, int mode) {
  int wave = threadIdx.x >> 6, lane = threadIdx.x & 63;
  int n = blockIdx.x * 4 + wave;
  if (n >= N) return;
  int half = lane >> 5;
  int hl = lane & 31;
  int start = row_ptr[n], end = row_ptr[n + 1];
  int dg = end - start; if (dg < 1) dg = 1;
  float inn = rsqrtf((float)dg);

  float acc[8];
#pragma unroll
  for (int k = 0; k < 8; ++k) acc[k] = 0.f;

  for (int base = start; base < end; base += 16) {
    int cs[8]; float cw[8];
    if (base + 16 <= end) {
#pragma unroll
      for (int k = 0; k < 8; ++k) {
        int2 e = edge_sw[base + half + 2 * k];
        cs[k] = e.x; cw[k] = __int_as_float(e.y);
      }
    } else {
#pragma unroll
      for (int k = 0; k < 8; ++k) {
        int i = base + half + 2 * k;
        cs[k] = 0; cw[k] = 0.f;
        if (i < end) { int2 e = edge_sw[i]; cs[k] = e.x; cw[k] = __int_as_float(e.y); }
      }
    }
    uint4 v[8];
#pragma unroll
    for (int k = 0; k < 8; ++k)
      v[k] = *(const uint4*)&x[(size_t)cs[k] * 256 + hl * 8];
#pragma unroll
    for (int k = 0; k < 8; ++k) {
      const uint32_t* p = (const uint32_t*)&v[k];
      float wk = cw[k];
#pragma unroll
      for (int q = 0; q < 4; ++q) {
        acc[2 * q]     += bf2f((ushort)(p[q] & 0xffffu)) * wk;
        acc[2 * q + 1] += bf2f((ushort)(p[q] >> 16)) * wk;
      }
    }
  }

#pragma unroll
  for (int k = 0; k < 8; ++k) acc[k] += __shfl_xor(acc[k], 32, 64);

  if (mode == 0) {
    if (half == 0) {
      int c0 = hl * 8;
      float4 ba = *(const float4*)(bias + c0);
      float4 bb = *(const float4*)(bias + c0 + 4);
      float h[8];
      h[0] = fmaxf(acc[0] * inn + ba.x, 0.f);
      h[1] = fmaxf(acc[1] * inn + ba.y, 0.f);
      h[2] = fmaxf(acc[2] * inn + ba.z, 0.f);
      h[3] = fmaxf(acc[3] * inn + ba.w, 0.f);
      h[4] = fmaxf(acc[4] * inn + bb.x, 0.f);
      h[5] = fmaxf(acc[5] * inn + bb.y, 0.f);
      h[6] = fmaxf(acc[6] * inn + bb.z, 0.f);
      h[7] = fmaxf(acc[7] * inn + bb.w, 0.f);
      *(float4*)&out32[(size_t)n * 256 + c0] = make_float4(h[0], h[1], h[2], h[3]);
      *(float4*)&out32[(size_t)n * 256 + c0 + 4] = make_float4(h[4], h[5], h[6], h[7]);
      uint4 ob; uint32_t* po = (uint32_t*)&ob;
#pragma unroll
      for (int q = 0; q < 4; ++q)
        po[q] = ((uint32_t)f2bf(h[2 * q + 1]) << 16) | (uint32_t)f2bf(h[2 * q]);
      *(uint4*)&outbf[(size_t)n * 256 + c0] = ob;
    }
  } else {
    float pacc[8];
#pragma unroll
    for (int k = 0; k < 8; ++k) pacc[k] = __shfl(acc[k], (lane & 15) + 16, 64);
    if (lane < 16) {
      int c0 = lane * 8;
      float4 b2a = *(const float4*)(bias + c0);
      float4 b2b = *(const float4*)(bias + c0 + 4);
      float4 b3a = *(const float4*)(bias + 128 + c0);
      float4 b3b = *(const float4*)(bias + 128 + c0 + 4);
      float4 nza = *(const float4*)(noise + (size_t)n * 128 + c0);
      float4 nzb = *(const float4*)(noise + (size_t)n * 128 + c0 + 4);
      float z[8];
      z[0] = fmaxf(acc[0] * inn + b2a.x, 0.f) + nza.x * expf(pacc[0] * inn + b3a.x);
      z[1] = fmaxf(acc[1] * inn + b2a.y, 0.f) + nza.y * expf(pacc[1] * inn + b3a.y);
      z[2] = fmaxf(acc[2] * inn + b2a.z, 0.f) + nza.z * expf(pacc[2] * inn + b3a.z);
      z[3] = fmaxf(acc[3] * inn + b2a.w, 0.f) + nza.w * expf(pacc[3] * inn + b3a.w);
      z[4] = fmaxf(acc[4] * inn + b2b.x, 0.f) + nzb.x * expf(pacc[4] * inn + b3b.x);
      z[5] = fmaxf(acc[5] * inn + b2b.y, 0.f) + nzb.y * expf(pacc[5] * inn + b3b.y);
      z[6] = fmaxf(acc[6] * inn + b2b.z, 0.f) + nzb.z * expf(pacc[6] * inn + b3b.z);
      z[7] = fmaxf(acc[7] * inn + b2b.w, 0.f) + nzb.w * expf(pacc[7] * inn + b3b.w);
      *(float4*)&out32[(size_t)n * 128 + c0] = make_float4(z[0], z[1], z[2], z[3]);
      *(float4*)&out32[(size_t)n * 128 + c0 + 4] = make_float4(z[4], z[5], z[6], z[7]);
    }
  }
}

// ---- barrier-free MFMA GEMM, 64-row tile: hwc = h_bf @ Wc (packed), bf16 out ----
__global__ __launch_bounds__(256, 4) void gemm_bf_kernel(
    const ushort* __restrict__ A, const ushort* __restrict__ Bp,
    ushort* __restrict__ Cbf, int M) {
  int t = threadIdx.x;
  int m0 = blockIdx.x * 64;
  int wave = t >> 6, lane = t & 63;
  int wm = wave * 16;
  int l15 = lane & 15, quad = lane >> 4;

  int r0 = m0 + wm + l15; if (r0 > M - 1) r0 = M - 1;
  const ushort* pa0 = A + (size_t)r0 * 256 + quad * 8;

  floatx4 acc[16];
#pragma unroll
  for (int j = 0; j < 16; ++j) acc[j] = (floatx4)(0.f);

#pragma unroll
  for (int ks = 0; ks < 8; ++ks) {
    short8 a0 = *(const short8*)(pa0 + ks * 32);
    const ushort* pb = Bp + ((ks * 4 + quad) * 16 + l15) * 128;
#pragma unroll
    for (int j = 0; j < 16; ++j) {
      short8 bv = *(const short8*)(pb + j * 8);
      acc[j] = __builtin_amdgcn_mfma_f32_16x16x32_bf16(a0, bv, acc[j], 0, 0, 0);
    }
  }

#pragma unroll
  for (int j = 0; j < 16; ++j) {
    int col = j * 16 + l15;
#pragma unroll
    for (int r = 0; r < 4; ++r) {
      int row = m0 + wm + quad * 4 + r;
      if (row < M) Cbf[(size_t)row * 256 + col] = f2bf(acc[j][r]);
    }
  }
}

extern "C" void kernel_launch(void* const* d_in, const int* in_sizes, int n_in,
                              void* d_out, int out_size, void* d_ws, size_t ws_size,
                              hipStream_t stream) {
  const float* features = (const float*)d_in[0];
  const float* noise    = (const float*)d_in[1];
  const float* W1 = (const float*)d_in[2];
  const float* b1 = (const float*)d_in[3];
  const float* W2 = (const float*)d_in[4];
  const float* b2 = (const float*)d_in[5];
  const float* W3 = (const float*)d_in[6];
  const float* b3 = (const float*)d_in[7];
  const float* fcW = (const float*)d_in[8];
  const int* src = (const int*)d_in[9];
  const int* dst = (const int*)d_in[10];
  const int N = in_sizes[0] / IN_DIM;
  const int E = in_sizes[9];

  float* out = (float*)d_out;
  float* z_out = out;                           // N x 128
  float* h_out = out + (size_t)N * OUT_DIM;     // N x 256
  float* s_out = h_out + (size_t)N * HID_DIM;   // N x 256

  char* w = (char*)d_ws;
  auto carve = [&](size_t bytes) {
    char* p = w;
    w += (bytes + 255) & ~(size_t)255;
    return p;
  };
  ushort* xw1_bf = (ushort*)carve((size_t)N * 256 * 2);
  ushort* h_bf   = (ushort*)carve((size_t)N * 256 * 2);
  ushort* hwc_bf = (ushort*)carve((size_t)N * 256 * 2);
  ushort* W1Tp = (ushort*)carve(256 * 256 * 2);
  ushort* WcTp = (ushort*)carve(256 * 256 * 2);
  ushort* fcWp = (ushort*)carve(256 * 256 * 2);
  float*  bcat = (float*)carve(256 * 4);
  int* degs    = (int*)carve((size_t)3 * N * 4);          // out_deg | in_deg | fill_cnt
  int* out_deg = degs;
  int* in_deg  = degs + N;
  int* fill_cnt = degs + 2 * N;
  int* row_ptr  = (int*)carve((size_t)(N + 1) * 4);
  int2* edge_sw = (int2*)carve((size_t)E * 8);

  hipMemsetAsync(degs, 0, (size_t)3 * N * 4, stream);
  int eblocks = ((E + 1) / 2 + 255) / 256;
  int gb = (N + 63) / 64;

  // A: degree atomics || packed W1Tp/WcTp/bcat prep || packed fcWp (all independent)
  deg_prep_kernel<<<eblocks + 512, 256, 0, stream>>>(src, dst, out_deg, in_deg, E, eblocks,
                                                     W1, W2, W3, b2, b3, fcW,
                                                     W1Tp, WcTp, bcat, fcWp);
  // MEGA: scan || seq_fts GEMM || XW1 GEMM (barrier-free, 64-row tiles)
  mega_kernel<<<2 * gb + 1, 256, 0, stream>>>(features, fcWp, W1Tp, s_out, xw1_bf,
                                              in_deg, row_ptr, N, N, gb);
  // CSR fill (needs row_ptr + out_deg)
  fill_kernel<<<eblocks, 256, 0, stream>>>(src, dst, row_ptr, fill_cnt, out_deg,
                                           edge_sw, E);
  // layer 1: h = relu(inn * agg(xw1) + b1)
  agg_kernel<<<(N + 3) / 4, 256, 0, stream>>>(xw1_bf, row_ptr, edge_sw, b1,
                                              (const float*)nullptr, h_out, h_bf, N, 0);
  // layer 2 dense part: hwc = h_bf @ [W2|W3]
  gemm_bf_kernel<<<gb, 256, 0, stream>>>(h_bf, WcTp, hwc_bf, N);
  // layer 2 + reparam: z = relu(inn*agg(hwc_m)+b2) + noise*exp(inn*agg(hwc_l)+b3)
  agg_kernel<<<(N + 3) / 4, 256, 0, stream>>>(hwc_bf, row_ptr, edge_sw, bcat,
                                              noise, z_out, (ushort*)nullptr, N, 1);
}

// Round 11
// 485.572 us; speedup vs baseline: 1.2521x; 1.2521x over previous
//
#include <hip/hip_runtime.h>
#include <hip/hip_bf16.h>
#include <stdint.h>
#include <math.h>

#define IN_DIM 256
#define HID_DIM 256
#define OUT_DIM 128

typedef __attribute__((ext_vector_type(8))) short short8;
typedef __attribute__((ext_vector_type(4))) float floatx4;

__device__ __forceinline__ float bf2f(ushort u) {
  union { uint32_t i; float f; } v; v.i = ((uint32_t)u) << 16; return v.f;
}
__device__ __forceinline__ ushort f2bf(float f) {
  union { float f; uint32_t u; } v; v.f = f;
  uint32_t u = v.u;
  uint32_t r = u + 0x7fffu + ((u >> 16) & 1u);  // RNE; finite values only here
  return (ushort)(r >> 16);
}
__device__ __forceinline__ short8 pack_bf16x8(float4 a, float4 b) {
  short8 r;
  r[0] = (short)f2bf(a.x); r[1] = (short)f2bf(a.y);
  r[2] = (short)f2bf(a.z); r[3] = (short)f2bf(a.w);
  r[4] = (short)f2bf(b.x); r[5] = (short)f2bf(b.y);
  r[6] = (short)f2bf(b.z); r[7] = (short)f2bf(b.w);
  return r;
}

// ---- dispatch A: degree counting (2 edges/thread) || W1T/WcT/bcat prep || fcW->bf16 ----
__global__ void deg_prep_kernel(const int* __restrict__ src, const int* __restrict__ dst,
                                int* __restrict__ out_deg, int* __restrict__ in_deg,
                                int E, int eblocks,
                                const float* __restrict__ W1, const float* __restrict__ W2,
                                const float* __restrict__ W3, const float* __restrict__ b2,
                                const float* __restrict__ b3, const float* __restrict__ fcW,
                                ushort* __restrict__ W1T, ushort* __restrict__ WcT,
                                float* __restrict__ bcat, ushort* __restrict__ fcWb) {
  int b = blockIdx.x, t = threadIdx.x;
  if (b < eblocks) {
    int e = (b * 256 + t) * 2;
    if (e + 1 < E) {
      int2 s = *(const int2*)(src + e);
      int2 d = *(const int2*)(dst + e);
      atomicAdd(&out_deg[s.x], 1);
      atomicAdd(&out_deg[s.y], 1);
      atomicAdd(&in_deg[d.x], 1);
      atomicAdd(&in_deg[d.y], 1);
    } else if (e < E) {
      atomicAdd(&out_deg[src[e]], 1);
      atomicAdd(&in_deg[dst[e]], 1);
    }
  } else if (b < eblocks + 256) {
    int k = b - eblocks;  // kdim 0..255
    int nn = t;           // outcol 0..255
    W1T[nn * 256 + k] = f2bf(W1[k * 256 + nn]);
    WcT[nn * 256 + k] = f2bf((nn < 128) ? W2[k * 128 + nn] : W3[k * 128 + (nn - 128)]);
    if (k == 0) bcat[nn] = (nn < 128) ? b2[nn] : b3[nn - 128];
  } else {
    int k = b - eblocks - 256;  // fcW row = outcol 0..255
    fcWb[k * 256 + t] = f2bf(fcW[k * 256 + t]);   // [outcol][kdim], coalesced copy
  }
}

// ---- MEGA: block 0 = scan(in_deg->row_ptr, batched int4);
//      blocks [1,1+gb)      = seq_fts GEMM (A=features fp32 streamed, B=fcWb via LDS, C fp32)
//      blocks [1+gb,1+2gb)  = XW1 GEMM    (A=features fp32 streamed, B=W1T via LDS, C bf16)
// HYBRID GEMM, M-TILE 64: B staged in LDS once per block (amortized across 4 waves --
// streaming B saturates L1 path, rounds 9/10); A-fragments are wave-private -> streamed
// from global, no A_lds. acc = 16 floatx4 (64 AGPR); (256,4) caps arch VGPR at 128,
// spill-free at this register profile (round-10 counters: VGPR 56, clean FETCH).
__global__ __launch_bounds__(256, 4) void mega_kernel(
    const float* __restrict__ feat, const ushort* __restrict__ fcWb,
    const ushort* __restrict__ W1T,
    float* __restrict__ s_out, ushort* __restrict__ xw1_bf,
    const int* __restrict__ in_deg, int* __restrict__ row_ptr, int n, int M, int gb) {
  __shared__ alignas(16) ushort B_lds[256 * 64];   // 32 KB
  int b = blockIdx.x;
  int t = threadIdx.x;

  if (b == 0) {
    // ============ scan role: latency-batched (8 int4 loads in flight) ============
    int* slds = (int*)B_lds;
    int CH = (n + 255) >> 8; CH = (CH + 3) & ~3;   // elems/thread, mult of 4
    int base = t * CH;
    int s = 0;
    if (base + CH <= n) {
      const int4* p = (const int4*)(in_deg + base);
      int c4 = CH >> 2;
#pragma unroll 8
      for (int j = 0; j < c4; ++j) { int4 q = p[j]; s += q.x + q.y + q.z + q.w; }
    } else {
      for (int i = base; i < n; ++i) s += in_deg[i];
    }
    slds[t] = s;
    __syncthreads();
    for (int off = 1; off < 256; off <<= 1) {
      int add = (t >= off) ? slds[t - off] : 0;
      __syncthreads();
      slds[t] += add;
      __syncthreads();
    }
    int run = slds[t] - s;                    // exclusive prefix
    if (t == 0) row_ptr[0] = 0;
    if (base + CH <= n) {
      const int4* p = (const int4*)(in_deg + base);
      int c4 = CH >> 2;
#pragma unroll 4
      for (int j = 0; j < c4; ++j) {
        int4 q = p[j];
        int i = base + j * 4;
        run += q.x; row_ptr[i + 1] = run;
        run += q.y; row_ptr[i + 2] = run;
        run += q.z; row_ptr[i + 3] = run;
        run += q.w; row_ptr[i + 4] = run;
      }
    } else {
      for (int i = base; i < n; ++i) { run += in_deg[i]; row_ptr[i + 1] = run; }
    }
    return;
  }

  // ============ GEMM roles ============
  int bb = b - 1;
  bool isSeq = bb < gb;
  int m0 = (isSeq ? bb : bb - gb) * 64;
  const ushort* Bsrc = isSeq ? fcWb : W1T;
  int wave = t >> 6, lane = t & 63;
  int wm = wave * 16;
  int l15 = lane & 15, quad = lane >> 4;

  int r0 = m0 + wm + l15; if (r0 > M - 1) r0 = M - 1;
  const float* pa0 = feat + (size_t)r0 * 256 + quad * 8;

  floatx4 acc[16];
#pragma unroll
  for (int j = 0; j < 16; ++j) acc[j] = (floatx4)(0.f);

  for (int kc = 0; kc < 256; kc += 64) {
#pragma unroll
    for (int r = 0; r < 8; ++r) {   // stage B: 256 rows x 64 cols bf16, swizzled
      int idx = t + r * 256;
      int row = idx >> 3;           // 0..255
      int c = (idx & 7) << 3;       // ushort offset 0..56
      int sc = c ^ ((row & 7) << 3);
      *(uint4*)&B_lds[row * 64 + sc] = *(const uint4*)(Bsrc + (size_t)row * 256 + kc + c);
    }
    __syncthreads();
#pragma unroll
    for (int ko = 0; ko < 2; ++ko) {
      float4 v0 = *(const float4*)(pa0 + kc + ko * 32);
      float4 v1 = *(const float4*)(pa0 + kc + ko * 32 + 4);
      short8 a0 = pack_bf16x8(v0, v1);
      int scr = (ko * 32 + quad * 8) ^ ((l15 & 7) << 3);
#pragma unroll
      for (int j = 0; j < 16; ++j) {
        short8 bv = *(const short8*)&B_lds[(j * 16 + l15) * 64 + scr];
        acc[j] = __builtin_amdgcn_mfma_f32_16x16x32_bf16(a0, bv, acc[j], 0, 0, 0);
      }
    }
    __syncthreads();
  }

  if (isSeq) {
#pragma unroll
    for (int j = 0; j < 16; ++j) {
      int col = j * 16 + l15;
#pragma unroll
      for (int r = 0; r < 4; ++r) {
        int row = m0 + wm + quad * 4 + r;
        if (row < M) s_out[(size_t)row * 256 + col] = acc[j][r];
      }
    }
  } else {
#pragma unroll
    for (int j = 0; j < 16; ++j) {
      int col = j * 16 + l15;
#pragma unroll
      for (int r = 0; r < 4; ++r) {
        int row = m0 + wm + quad * 4 + r;
        if (row < M) xw1_bf[(size_t)row * 256 + col] = f2bf(acc[j][r]);
      }
    }
  }
}

// ---- bucket edges by dst (CSR fill); 2 edges/thread; record {src, bits(rsqrt(out_deg))} ----
__global__ void fill_kernel(const int* __restrict__ src, const int* __restrict__ dst,
                            const int* __restrict__ row_ptr, int* __restrict__ fill_cnt,
                            const int* __restrict__ out_deg,
                            int2* __restrict__ edge_sw, int E) {
  int e = (blockIdx.x * 256 + threadIdx.x) * 2;
  if (e + 1 < E) {
    int2 s = *(const int2*)(src + e);
    int2 d = *(const int2*)(dst + e);
    int pos0 = row_ptr[d.x] + atomicAdd(&fill_cnt[d.x], 1);
    int od0 = out_deg[s.x]; if (od0 < 1) od0 = 1;
    int2 r0; r0.x = s.x; r0.y = __float_as_int(rsqrtf((float)od0));
    edge_sw[pos0] = r0;
    int pos1 = row_ptr[d.y] + atomicAdd(&fill_cnt[d.y], 1);
    int od1 = out_deg[s.y]; if (od1 < 1) od1 = 1;
    int2 r1; r1.x = s.y; r1.y = __float_as_int(rsqrtf((float)od1));
    edge_sw[pos1] = r1;
  } else if (e < E) {
    int d = dst[e]; int s = src[e];
    int pos = row_ptr[d] + atomicAdd(&fill_cnt[d], 1);
    int od = out_deg[s]; if (od < 1) od = 1;
    int2 r; r.x = s; r.y = __float_as_int(rsqrtf((float)od));
    edge_sw[pos] = r;
  }
}

// ---- aggregation over TRANSFORMED features with fused epilogue ----
// mode 0 (h):  out32[n][256] = relu(acc*inn + bias[dim]), outbf = bf16 copy
// mode 1 (z):  dims 0..127 = mean-part, 128..255 = logstd-part ->
//              z[n][c] = relu(am*inn+b2[c]) + noise[n][c]*exp(al*inn+b3[c])
__global__ __launch_bounds__(256) void agg_kernel(
    const ushort* __restrict__ x, const int* __restrict__ row_ptr,
    const int2* __restrict__ edge_sw,
    const float* __restrict__ bias, const float* __restrict__ noise,
    float* __restrict__ out32, ushort* __restrict__ outbf, int N, int mode) {
  int wave = threadIdx.x >> 6, lane = threadIdx.x & 63;
  int n = blockIdx.x * 4 + wave;
  if (n >= N) return;
  int half = lane >> 5;
  int hl = lane & 31;
  int start = row_ptr[n], end = row_ptr[n + 1];
  int dg = end - start; if (dg < 1) dg = 1;
  float inn = rsqrtf((float)dg);

  float acc[8];
#pragma unroll
  for (int k = 0; k < 8; ++k) acc[k] = 0.f;

  for (int base = start; base < end; base += 16) {
    int cs[8]; float cw[8];
    if (base + 16 <= end) {
#pragma unroll
      for (int k = 0; k < 8; ++k) {
        int2 e = edge_sw[base + half + 2 * k];
        cs[k] = e.x; cw[k] = __int_as_float(e.y);
      }
    } else {
#pragma unroll
      for (int k = 0; k < 8; ++k) {
        int i = base + half + 2 * k;
        cs[k] = 0; cw[k] = 0.f;
        if (i < end) { int2 e = edge_sw[i]; cs[k] = e.x; cw[k] = __int_as_float(e.y); }
      }
    }
    uint4 v[8];
#pragma unroll
    for (int k = 0; k < 8; ++k)
      v[k] = *(const uint4*)&x[(size_t)cs[k] * 256 + hl * 8];
#pragma unroll
    for (int k = 0; k < 8; ++k) {
      const uint32_t* p = (const uint32_t*)&v[k];
      float wk = cw[k];
#pragma unroll
      for (int q = 0; q < 4; ++q) {
        acc[2 * q]     += bf2f((ushort)(p[q] & 0xffffu)) * wk;
        acc[2 * q + 1] += bf2f((ushort)(p[q] >> 16)) * wk;
      }
    }
  }

#pragma unroll
  for (int k = 0; k < 8; ++k) acc[k] += __shfl_xor(acc[k], 32, 64);

  if (mode == 0) {
    if (half == 0) {
      int c0 = hl * 8;
      float4 ba = *(const float4*)(bias + c0);
      float4 bb = *(const float4*)(bias + c0 + 4);
      float h[8];
      h[0] = fmaxf(acc[0] * inn + ba.x, 0.f);
      h[1] = fmaxf(acc[1] * inn + ba.y, 0.f);
      h[2] = fmaxf(acc[2] * inn + ba.z, 0.f);
      h[3] = fmaxf(acc[3] * inn + ba.w, 0.f);
      h[4] = fmaxf(acc[4] * inn + bb.x, 0.f);
      h[5] = fmaxf(acc[5] * inn + bb.y, 0.f);
      h[6] = fmaxf(acc[6] * inn + bb.z, 0.f);
      h[7] = fmaxf(acc[7] * inn + bb.w, 0.f);
      *(float4*)&out32[(size_t)n * 256 + c0] = make_float4(h[0], h[1], h[2], h[3]);
      *(float4*)&out32[(size_t)n * 256 + c0 + 4] = make_float4(h[4], h[5], h[6], h[7]);
      uint4 ob; uint32_t* po = (uint32_t*)&ob;
#pragma unroll
      for (int q = 0; q < 4; ++q)
        po[q] = ((uint32_t)f2bf(h[2 * q + 1]) << 16) | (uint32_t)f2bf(h[2 * q]);
      *(uint4*)&outbf[(size_t)n * 256 + c0] = ob;
    }
  } else {
    float pacc[8];
#pragma unroll
    for (int k = 0; k < 8; ++k) pacc[k] = __shfl(acc[k], (lane & 15) + 16, 64);
    if (lane < 16) {
      int c0 = lane * 8;
      float4 b2a = *(const float4*)(bias + c0);
      float4 b2b = *(const float4*)(bias + c0 + 4);
      float4 b3a = *(const float4*)(bias + 128 + c0);
      float4 b3b = *(const float4*)(bias + 128 + c0 + 4);
      float4 nza = *(const float4*)(noise + (size_t)n * 128 + c0);
      float4 nzb = *(const float4*)(noise + (size_t)n * 128 + c0 + 4);
      float z[8];
      z[0] = fmaxf(acc[0] * inn + b2a.x, 0.f) + nza.x * expf(pacc[0] * inn + b3a.x);
      z[1] = fmaxf(acc[1] * inn + b2a.y, 0.f) + nza.y * expf(pacc[1] * inn + b3a.y);
      z[2] = fmaxf(acc[2] * inn + b2a.z, 0.f) + nza.z * expf(pacc[2] * inn + b3a.z);
      z[3] = fmaxf(acc[3] * inn + b2a.w, 0.f) + nza.w * expf(pacc[3] * inn + b3a.w);
      z[4] = fmaxf(acc[4] * inn + b2b.x, 0.f) + nzb.x * expf(pacc[4] * inn + b3b.x);
      z[5] = fmaxf(acc[5] * inn + b2b.y, 0.f) + nzb.y * expf(pacc[5] * inn + b3b.y);
      z[6] = fmaxf(acc[6] * inn + b2b.z, 0.f) + nzb.z * expf(pacc[6] * inn + b3b.z);
      z[7] = fmaxf(acc[7] * inn + b2b.w, 0.f) + nzb.w * expf(pacc[7] * inn + b3b.w);
      *(float4*)&out32[(size_t)n * 128 + c0] = make_float4(z[0], z[1], z[2], z[3]);
      *(float4*)&out32[(size_t)n * 128 + c0 + 4] = make_float4(z[4], z[5], z[6], z[7]);
    }
  }
}

// ---- hybrid MFMA GEMM, M-TILE 64: hwc = h_bf @ WcT; B via LDS, A (bf16) streamed ----
__global__ __launch_bounds__(256, 4) void gemm_bf_kernel(
    const ushort* __restrict__ A, const ushort* __restrict__ BT,
    ushort* __restrict__ Cbf, int M) {
  __shared__ alignas(16) ushort B_lds[256 * 64];   // 32 KB
  int t = threadIdx.x;
  int m0 = blockIdx.x * 64;
  int wave = t >> 6, lane = t & 63;
  int wm = wave * 16;
  int l15 = lane & 15, quad = lane >> 4;

  int r0 = m0 + wm + l15; if (r0 > M - 1) r0 = M - 1;
  const ushort* pa0 = A + (size_t)r0 * 256 + quad * 8;

  floatx4 acc[16];
#pragma unroll
  for (int j = 0; j < 16; ++j) acc[j] = (floatx4)(0.f);

  for (int kc = 0; kc < 256; kc += 64) {
#pragma unroll
    for (int r = 0; r < 8; ++r) {   // stage B, swizzled
      int idx = t + r * 256;
      int row = idx >> 3;
      int c = (idx & 7) << 3;
      int sc = c ^ ((row & 7) << 3);
      *(uint4*)&B_lds[row * 64 + sc] = *(const uint4*)(BT + (size_t)row * 256 + kc + c);
    }
    __syncthreads();
#pragma unroll
    for (int ko = 0; ko < 2; ++ko) {
      short8 a0 = *(const short8*)(pa0 + kc + ko * 32);
      int scr = (ko * 32 + quad * 8) ^ ((l15 & 7) << 3);
#pragma unroll
      for (int j = 0; j < 16; ++j) {
        short8 bv = *(const short8*)&B_lds[(j * 16 + l15) * 64 + scr];
        acc[j] = __builtin_amdgcn_mfma_f32_16x16x32_bf16(a0, bv, acc[j], 0, 0, 0);
      }
    }
    __syncthreads();
  }

#pragma unroll
  for (int j = 0; j < 16; ++j) {
    int col = j * 16 + l15;
#pragma unroll
    for (int r = 0; r < 4; ++r) {
      int row = m0 + wm + quad * 4 + r;
      if (row < M) Cbf[(size_t)row * 256 + col] = f2bf(acc[j][r]);
    }
  }
}

extern "C" void kernel_launch(void* const* d_in, const int* in_sizes, int n_in,
                              void* d_out, int out_size, void* d_ws, size_t ws_size,
                              hipStream_t stream) {
  const float* features = (const float*)d_in[0];
  const float* noise    = (const float*)d_in[1];
  const float* W1 = (const float*)d_in[2];
  const float* b1 = (const float*)d_in[3];
  const float* W2 = (const float*)d_in[4];
  const float* b2 = (const float*)d_in[5];
  const float* W3 = (const float*)d_in[6];
  const float* b3 = (const float*)d_in[7];
  const float* fcW = (const float*)d_in[8];
  const int* src = (const int*)d_in[9];
  const int* dst = (const int*)d_in[10];
  const int N = in_sizes[0] / IN_DIM;
  const int E = in_sizes[9];

  float* out = (float*)d_out;
  float* z_out = out;                           // N x 128
  float* h_out = out + (size_t)N * OUT_DIM;     // N x 256
  float* s_out = h_out + (size_t)N * HID_DIM;   // N x 256

  char* w = (char*)d_ws;
  auto carve = [&](size_t bytes) {
    char* p = w;
    w += (bytes + 255) & ~(size_t)255;
    return p;
  };
  ushort* xw1_bf = (ushort*)carve((size_t)N * 256 * 2);
  ushort* h_bf   = (ushort*)carve((size_t)N * 256 * 2);
  ushort* hwc_bf = (ushort*)carve((size_t)N * 256 * 2);
  ushort* W1T  = (ushort*)carve(256 * 256 * 2);
  ushort* WcT  = (ushort*)carve(256 * 256 * 2);
  ushort* fcWb = (ushort*)carve(256 * 256 * 2);
  float*  bcat = (float*)carve(256 * 4);
  int* degs    = (int*)carve((size_t)3 * N * 4);          // out_deg | in_deg | fill_cnt
  int* out_deg = degs;
  int* in_deg  = degs + N;
  int* fill_cnt = degs + 2 * N;
  int* row_ptr  = (int*)carve((size_t)(N + 1) * 4);
  int2* edge_sw = (int2*)carve((size_t)E * 8);

  hipMemsetAsync(degs, 0, (size_t)3 * N * 4, stream);
  int eblocks = ((E + 1) / 2 + 255) / 256;
  int gb = (N + 63) / 64;

  // A: degree atomics || W1T/WcT/bcat prep || fcW bf16 convert (all independent)
  deg_prep_kernel<<<eblocks + 512, 256, 0, stream>>>(src, dst, out_deg, in_deg, E, eblocks,
                                                     W1, W2, W3, b2, b3, fcW,
                                                     W1T, WcT, bcat, fcWb);
  // MEGA: scan || seq_fts GEMM || XW1 GEMM (hybrid B-LDS/A-stream, M-64)
  mega_kernel<<<2 * gb + 1, 256, 0, stream>>>(features, fcWb, W1T, s_out, xw1_bf,
                                              in_deg, row_ptr, N, N, gb);
  // CSR fill (needs row_ptr + out_deg)
  fill_kernel<<<eblocks, 256, 0, stream>>>(src, dst, row_ptr, fill_cnt, out_deg,
                                           edge_sw, E);
  // layer 1: h = relu(inn * agg(xw1) + b1)
  agg_kernel<<<(N + 3) / 4, 256, 0, stream>>>(xw1_bf, row_ptr, edge_sw, b1,
                                              (const float*)nullptr, h_out, h_bf, N, 0);
  // layer 2 dense part: hwc = h_bf @ [W2|W3]
  gemm_bf_kernel<<<gb, 256, 0, stream>>>(h_bf, WcT, hwc_bf, N);
  // layer 2 + reparam: z = relu(inn*agg(hwc_m)+b2) + noise*exp(inn*agg(hwc_l)+b3)
  agg_kernel<<<(N + 3) / 4, 256, 0, stream>>>(hwc_bf, row_ptr, edge_sw, bcat,
                                              noise, z_out, (ushort*)nullptr, N, 1);
}